// Round 23
// baseline (263.113 us; speedup 1.0000x reference)
//
#include <hip/hip_runtime.h>
#include <hip/hip_bf16.h>
#include <cmath>
#include <type_traits>

#define BC     4
#define SEQ    2048
#define DMODEL 1024
#define NHEAD  16
#define HD     64
#define ASCALE 0.125f
#define LOG2E  1.44269504f

typedef __bf16 bf16x8 __attribute__((ext_vector_type(8)));
typedef __bf16 bf16x4 __attribute__((ext_vector_type(4)));
typedef float  f32x4  __attribute__((ext_vector_type(4)));

__device__ __forceinline__ f32x4 mfma16x16x32(bf16x8 a, bf16x8 b, f32x4 c) {
    return __builtin_amdgcn_mfma_f32_16x16x32_bf16(a, b, c, 0, 0, 0);
}

__device__ __forceinline__ float fexp2(float x) {   // raw v_exp_f32 (2^x)
    return __builtin_amdgcn_exp2f(x);
}

__device__ __forceinline__ void gload_lds16(const __bf16* g, __bf16* l) {
    __builtin_amdgcn_global_load_lds(
        (const __attribute__((address_space(1))) void*)g,
        (__attribute__((address_space(3))) void*)l, 16, 0, 0);
}

__global__ __launch_bounds__(256) void cvt_w(const float* __restrict__ a,
                                             const float* __restrict__ b,
                                             const float* __restrict__ c,
                                             const float* __restrict__ d,
                                             __bf16* __restrict__ oa,
                                             __bf16* __restrict__ ob,
                                             __bf16* __restrict__ oc,
                                             __bf16* __restrict__ od) {
    const float* in; __bf16* out;
    if (blockIdx.y == 0)      { in = a; out = oa; }
    else if (blockIdx.y == 1) { in = b; out = ob; }
    else if (blockIdx.y == 2) { in = c; out = oc; }
    else                      { in = d; out = od; }
    const size_t i = ((size_t)blockIdx.x * 256 + threadIdx.x) * 8;
    float4 f0 = *(const float4*)(in + i);
    float4 f1 = *(const float4*)(in + i + 4);
    bf16x8 o;
    o[0] = (__bf16)f0.x; o[1] = (__bf16)f0.y; o[2] = (__bf16)f0.z; o[3] = (__bf16)f0.w;
    o[4] = (__bf16)f1.x; o[5] = (__bf16)f1.y; o[6] = (__bf16)f1.z; o[7] = (__bf16)f1.w;
    *(bf16x8*)(out + i) = o;
}

// Batched Q/K/V projection GEMMs, 128x256 tile, 8 waves, DEPTH-2 register
// pipeline: loads for K-step t+2 issue during step t (two compute phases of
// latency cover). Raw-barrier discipline; no vmcnt drain in the loop.
__global__ __launch_bounds__(512) void qkv_gemm(const float* __restrict__ Aq,
                                                const float* __restrict__ Ak,
                                                const float* __restrict__ Av,
                                                const __bf16* __restrict__ Wqb,
                                                const __bf16* __restrict__ Wkb,
                                                const __bf16* __restrict__ Wvb,
                                                const float* __restrict__ bq,
                                                const float* __restrict__ bk,
                                                const float* __restrict__ bv,
                                                __bf16* __restrict__ oq,
                                                __bf16* __restrict__ ok,
                                                __bf16* __restrict__ ov) {
    constexpr int K = DMODEL, N = DMODEL;
    __shared__ __bf16 As[128 * 64];
    __shared__ __bf16 Bs[256 * 64];
    const int z = blockIdx.z;
    const float* A; const __bf16* W; const float* bias; __bf16* out; float scale; bool vt;
    if (z == 0)      { A = Aq; W = Wqb; bias = bq; out = oq; scale = ASCALE * LOG2E; vt = false; }
    else if (z == 1) { A = Ak; W = Wkb; bias = bk; out = ok; scale = 1.f; vt = false; }
    else             { A = Av; W = Wvb; bias = bv; out = ov; scale = 1.f; vt = true; }

    const int tid = threadIdx.x;
    const int lane = tid & 63;
    const int wid = tid >> 6;          // 0..7
    const int lr = lane & 15;
    const int lg = lane >> 4;
    const int wr = (wid >> 2) * 64;    // 0,64
    const int wc = (wid & 3) * 64;     // 0,64,128,192

    // XCD-locality decode (grid.x = 256)
    const int flat = blockIdx.x;
    const int xcd = flat & 7;
    const int slot = flat >> 3;        // 0..31
    const int bm = (xcd + 8 * (slot >> 2)) * 128;
    const int bn = (slot & 3) * 256;

    f32x4 acc[4][4] = {};

    // depth-2 pipeline: slot A holds step t's data, slot B holds t+1's.
    float4 aA0[2], aA1[2], aB0[2], aB1[2];
    bf16x8 wA[4], wB[4];

    #pragma unroll
    for (int i = 0; i < 2; ++i) {      // step 0 loads
        const int p = tid + 512 * i;
        const int row = p >> 3, c = p & 7;
        const float* ap = A + (size_t)(bm + row) * K + c * 8;
        aA0[i] = ((const float4*)ap)[0];
        aA1[i] = ((const float4*)ap)[1];
    }
    #pragma unroll
    for (int i = 0; i < 4; ++i) {
        const int p = tid + 512 * i;
        const int row = p >> 3, c = p & 7;
        wA[i] = *(const bf16x8*)(W + (size_t)(bn + row) * K + c * 8);
    }
    #pragma unroll
    for (int i = 0; i < 2; ++i) {      // step 1 loads (in flight through step 0)
        const int p = tid + 512 * i;
        const int row = p >> 3, c = p & 7;
        const float* ap = A + (size_t)(bm + row) * K + 64 + c * 8;
        aB0[i] = ((const float4*)ap)[0];
        aB1[i] = ((const float4*)ap)[1];
    }
    #pragma unroll
    for (int i = 0; i < 4; ++i) {
        const int p = tid + 512 * i;
        const int row = p >> 3, c = p & 7;
        wB[i] = *(const bf16x8*)(W + (size_t)(bn + row) * K + 64 + c * 8);
    }

    #pragma unroll 2
    for (int t = 0; t < K / 64; ++t) {
        const int k0 = t * 64;
        const bool even = (t & 1) == 0;   // even steps commit slot A, odd slot B
        // commit current step's regs (per-wave vmcnt waits here, staggered)
        #pragma unroll
        for (int i = 0; i < 2; ++i) {
            const int p = tid + 512 * i;
            const int row = p >> 3, c = p & 7;
            const float4 f0 = even ? aA0[i] : aB0[i];
            const float4 f1 = even ? aA1[i] : aB1[i];
            bf16x8 v;
            v[0] = (__bf16)f0.x; v[1] = (__bf16)f0.y;
            v[2] = (__bf16)f0.z; v[3] = (__bf16)f0.w;
            v[4] = (__bf16)f1.x; v[5] = (__bf16)f1.y;
            v[6] = (__bf16)f1.z; v[7] = (__bf16)f1.w;
            *(bf16x8*)&As[row * 64 + ((c ^ (row & 7)) * 8)] = v;
        }
        #pragma unroll
        for (int i = 0; i < 4; ++i) {
            const int p = tid + 512 * i;
            const int row = p >> 3, c = p & 7;
            *(bf16x8*)&Bs[row * 64 + ((c ^ (row & 7)) * 8)] = even ? wA[i] : wB[i];
        }
        asm volatile("s_waitcnt lgkmcnt(0)" ::: "memory");   // ds_writes visible
        __builtin_amdgcn_s_barrier();                        // raw: no vmcnt drain

        if (k0 + 128 < K) {   // issue step t+2's loads into the freed slot;
            const int k2 = k0 + 128;   // ~2 compute phases of latency cover
            #pragma unroll
            for (int i = 0; i < 2; ++i) {
                const int p = tid + 512 * i;
                const int row = p >> 3, c = p & 7;
                const float* ap = A + (size_t)(bm + row) * K + k2 + c * 8;
                if (even) { aA0[i] = ((const float4*)ap)[0]; aA1[i] = ((const float4*)ap)[1]; }
                else      { aB0[i] = ((const float4*)ap)[0]; aB1[i] = ((const float4*)ap)[1]; }
            }
            #pragma unroll
            for (int i = 0; i < 4; ++i) {
                const int p = tid + 512 * i;
                const int row = p >> 3, c = p & 7;
                const bf16x8 wv = *(const bf16x8*)(W + (size_t)(bn + row) * K + k2 + c * 8);
                if (even) wA[i] = wv; else wB[i] = wv;
            }
        }

        __builtin_amdgcn_s_setprio(1);
        #pragma unroll
        for (int kk = 0; kk < 2; ++kk) {
            bf16x8 af[4], bfg[4];
            #pragma unroll
            for (int m = 0; m < 4; ++m) {
                const int row = wr + m * 16 + lr;
                af[m] = *(const bf16x8*)&As[row * 64 + ((kk * 4 + lg) ^ (row & 7)) * 8];
            }
            #pragma unroll
            for (int n = 0; n < 4; ++n) {
                const int row = wc + n * 16 + lr;
                bfg[n] = *(const bf16x8*)&Bs[row * 64 + ((kk * 4 + lg) ^ (row & 7)) * 8];
            }
            #pragma unroll
            for (int m = 0; m < 4; ++m)
                #pragma unroll
                for (int n = 0; n < 4; ++n)
                    acc[m][n] = mfma16x16x32(af[m], bfg[n], acc[m][n]);
        }
        __builtin_amdgcn_s_setprio(0);

        __builtin_amdgcn_s_barrier();          // raw: reads done via MFMA deps
        asm volatile("" ::: "memory");
    }

    #pragma unroll
    for (int n = 0; n < 4; ++n) {
        const int col = bn + wc + n * 16 + lr;
        const float bb = bias[col];
        #pragma unroll
        for (int m = 0; m < 4; ++m) {
            const int row0 = bm + wr + m * 16 + lg * 4;
            if (vt) {
                const int h = col >> 6, hd = col & 63;
                const int b = row0 >> 11, s = row0 & 2047;
                bf16x4 pk;
                #pragma unroll
                for (int r = 0; r < 4; ++r) pk[r] = (__bf16)((acc[m][n][r] + bb) * scale);
                *(bf16x4*)(out + (((size_t)b * NHEAD + h) * HD + hd) * SEQ + s) = pk;
            } else {
                #pragma unroll
                for (int r = 0; r < 4; ++r)
                    out[(size_t)(row0 + r) * N + col] = (__bf16)((acc[m][n][r] + bb) * scale);
            }
        }
    }
}

// Fused tail: blocks [0,512) = O-projection GEMM (8-wave, 64x32 wave tile);
// blocks [512,1536) = mean-over-heads attention weights.
__global__ __launch_bounds__(512) void tail_fused(const __bf16* __restrict__ ob,
                                                  const __bf16* __restrict__ Wob,
                                                  const float* __restrict__ bo,
                                                  float* __restrict__ out,
                                                  const __bf16* __restrict__ q,
                                                  const __bf16* __restrict__ k,
                                                  const float* __restrict__ mbuf,
                                                  const float* __restrict__ lbuf,
                                                  float* __restrict__ wout) {
    __shared__ __bf16 smem[2][128][64];
    const int tid = threadIdx.x;
    const int lane = tid & 63;
    const int wid = tid >> 6;            // 0..7
    const int lr = lane & 15;
    const int lg = lane >> 4;

    if (blockIdx.x < 512) {
        constexpr int K = DMODEL, N = DMODEL;
        __bf16* As = &smem[0][0][0];
        __bf16* Bs = &smem[1][0][0];
        const int bx = blockIdx.x;
        const int bm = (bx & 63) * 128;
        const int bn = (bx >> 6) * 128;
        const int wr = (wid >> 2) * 64;
        const int wc = (wid & 3) * 32;

        f32x4 acc[4][2] = {};

        for (int k0 = 0; k0 < K; k0 += 64) {
            #pragma unroll
            for (int i = 0; i < 2; ++i) {
                const int p = tid + 512 * i;
                const int row = p >> 3, c = p & 7;
                const int csrc = ((c ^ (row & 7)) * 8);
                gload_lds16(Wob + (size_t)(bn + row) * K + k0 + csrc, &Bs[p * 8]);
                gload_lds16(ob  + (size_t)(bm + row) * K + k0 + csrc, &As[p * 8]);
            }
            __syncthreads();

            #pragma unroll
            for (int kk = 0; kk < 2; ++kk) {
                bf16x8 af[4], bfg[2];
                #pragma unroll
                for (int m = 0; m < 4; ++m) {
                    const int row = wr + m * 16 + lr;
                    af[m] = *(const bf16x8*)&As[row * 64 + ((kk * 4 + lg) ^ (row & 7)) * 8];
                }
                #pragma unroll
                for (int n = 0; n < 2; ++n) {
                    const int row = wc + n * 16 + lr;
                    bfg[n] = *(const bf16x8*)&Bs[row * 64 + ((kk * 4 + lg) ^ (row & 7)) * 8];
                }
                #pragma unroll
                for (int m = 0; m < 4; ++m)
                    #pragma unroll
                    for (int n = 0; n < 2; ++n)
                        acc[m][n] = mfma16x16x32(af[m], bfg[n], acc[m][n]);
            }
            __syncthreads();
        }

        #pragma unroll
        for (int n = 0; n < 2; ++n) {
            const int col = bn + wc + n * 16 + lr;
            const float bb = bo[col];
            #pragma unroll
            for (int m = 0; m < 4; ++m) {
                const int row0 = bm + wr + m * 16 + lg * 4;
                #pragma unroll
                for (int r = 0; r < 4; ++r)
                    out[(size_t)(row0 + r) * N + col] = acc[m][n][r] + bb;
            }
        }
        return;
    }

    {
        const int flat = blockIdx.x - 512;
        const int xcd = flat & 7;
        const int slot = flat >> 3;
        const int gi = slot >> 4;
        const int st = slot & 15;
        const int b = gi & 3;
        const int t2 = (gi >> 2) ? (15 - xcd) : xcd;

        const int myq = st * 128 + wid * 16 + lr;
        const int k0 = t2 * 128;

        float* wp = wout + (size_t)(b * SEQ + myq) * SEQ + k0 + lg * 4;

        if (t2 > st) {
            const f32x4 zz = {0.f, 0.f, 0.f, 0.f};
            #pragma unroll
            for (int ts = 0; ts < 8; ++ts) *(f32x4*)(wp + ts * 16) = zz;
            return;
        }
        const bool needmask = (t2 == st);

        f32x4 rm[4], rl[4];
        {
            const float* mp = mbuf + ((size_t)b * SEQ + myq) * NHEAD;
            const float* lp = lbuf + ((size_t)b * SEQ + myq) * NHEAD;
            #pragma unroll
            for (int i = 0; i < 4; ++i) rm[i] = *(const f32x4*)(mp + i * 4);
            #pragma unroll
            for (int i = 0; i < 4; ++i) {
                f32x4 t = *(const f32x4*)(lp + i * 4);
                #pragma unroll
                for (int r = 0; r < 4; ++r) rl[i][r] = 1.f / (t[r] * (float)NHEAD);
            }
        }

        const int srow = tid >> 2;
        const int scb = (tid & 3) * 2;
        const int rsw = (lr & 7);
        const __bf16* krow = k + (size_t)(b * SEQ + k0 + srow) * DMODEL + scb * 8;
        const __bf16* qbase = q + (size_t)(b * SEQ + myq) * DMODEL + lg * 8;

        {
            bf16x8 kr[2];
            #pragma unroll
            for (int c = 0; c < 2; ++c) kr[c] = *(const bf16x8*)(krow + c * 8);
            #pragma unroll
            for (int c = 0; c < 2; ++c)
                *(bf16x8*)&smem[0][srow][((scb + c) ^ (srow & 7)) * 8] = kr[c];
        }
        bf16x8 qna = ((const bf16x8*)qbase)[0];
        bf16x8 qnb = *(const bf16x8*)(qbase + 32);

        f32x4 wacc[8] = {};
        __syncthreads();

        #pragma unroll
        for (int h = 0; h < NHEAD; ++h) {
            const int cur = h & 1;
            bf16x8 kr[2];
            if (h + 1 < NHEAD) {
                const __bf16* kp = krow + (h + 1) * HD;
                #pragma unroll
                for (int c = 0; c < 2; ++c) kr[c] = *(const bf16x8*)(kp + c * 8);
            }
            const bf16x8 qf0 = qna, qf1 = qnb;
            if (h + 1 < NHEAD) {
                qna = *(const bf16x8*)(qbase + (h + 1) * HD);
                qnb = *(const bf16x8*)(qbase + (h + 1) * HD + 32);
            }
            const float rmh = rm[h >> 2][h & 3];
            const float rlh = rl[h >> 2][h & 3];

            #pragma unroll
            for (int ts = 0; ts < 8; ++ts) {
                bf16x8 kf0 = *(const bf16x8*)&smem[cur][ts * 16 + lr][(lg ^ rsw) * 8];
                bf16x8 kf1 = *(const bf16x8*)&smem[cur][ts * 16 + lr][((4 + lg) ^ rsw) * 8];
                f32x4 zz = {0.f, 0.f, 0.f, 0.f};
                zz = mfma16x16x32(kf0, qf0, zz);
                zz = mfma16x16x32(kf1, qf1, zz);
                if (needmask) {
                    #pragma unroll
                    for (int r = 0; r < 4; ++r) {
                        float e = 0.f;
                        if (k0 + ts * 16 + lg * 4 + r <= myq)
                            e = fexp2(zz[r] - rmh) * rlh;
                        wacc[ts][r] += e;
                    }
                } else {
                    #pragma unroll
                    for (int r = 0; r < 4; ++r)
                        wacc[ts][r] += fexp2(zz[r] - rmh) * rlh;
                }
            }

            if (h + 1 < NHEAD) {
                #pragma unroll
                for (int c = 0; c < 2; ++c)
                    *(bf16x8*)&smem[cur ^ 1][srow][((scb + c) ^ (srow & 7)) * 8] = kr[c];
            }
            __syncthreads();
        }

        #pragma unroll
        for (int ts = 0; ts < 8; ++ts)
            *(f32x4*)(wp + ts * 16) = wacc[ts];
    }
}

// Causal flash attention, 128 q rows x 8 waves per block, log2-domain softmax.
__global__ __launch_bounds__(512) void flash_fwd(const __bf16* __restrict__ q,
                                                 const __bf16* __restrict__ k,
                                                 const __bf16* __restrict__ vt,
                                                 __bf16* __restrict__ o,
                                                 float* __restrict__ mbuf,
                                                 float* __restrict__ lbuf) {
    __shared__ __bf16 Ks[2][64][64];
    __shared__ __bf16 Vs[2][64][64];
    __shared__ __bf16 Ps[8][16][64];
    const int tid = threadIdx.x;
    const int lane = tid & 63;
    const int wid = tid >> 6;
    const int lr = lane & 15;
    const int lg = lane >> 4;

    const int flat = blockIdx.x;
    const int xcd = flat & 7;
    const int slot = flat >> 3;
    const int group = xcd * 8 + (slot >> 4);
    const int b = group >> 4;
    const int h = group & 15;
    const int qt = 15 - (slot & 15);

    const int qr = qt * 128 + wid * 16;
    const int myq = qr + lr;
    const int dtile = qr >> 6;

    bf16x8 qf0, qf1;
    {
        const __bf16* qp = q + (size_t)(b * SEQ + myq) * DMODEL + h * HD + lg * 8;
        qf0 = ((const bf16x8*)qp)[0];
        qf1 = *(const bf16x8*)(qp + 32);
    }

    float m_run = -INFINITY;
    float l_run = 0.f;
    f32x4 oacc[4] = {};

    const int srow = tid >> 3;
    const int sc = tid & 7;
    const int swz = (sc ^ (srow & 7)) * 8;
    const int rsw = (lr & 7);
    const int nt = 2 * qt + 2;

    const __bf16* kbase = k + (size_t)(b * SEQ + srow) * DMODEL + h * HD + sc * 8;
    const __bf16* vbase = vt + ((size_t)(b * NHEAD + h) * HD + srow) * SEQ + sc * 8;

    {
        bf16x8 kr = *(const bf16x8*)kbase;
        bf16x8 vr = *(const bf16x8*)vbase;
        *(bf16x8*)&Ks[0][srow][swz] = kr;
        *(bf16x8*)&Vs[0][srow][swz] = vr;
    }
    __syncthreads();

    for (int t = 0; t < nt; ++t) {
        const int buf = t & 1;
        const bool pre = (t + 1 < nt);
        bf16x8 kr, vr;
        if (pre) {
            kr = *(const bf16x8*)(kbase + (size_t)(t + 1) * 64 * DMODEL);
            vr = *(const bf16x8*)(vbase + (t + 1) * 64);
        }

        if (t <= dtile) {
            f32x4 z[4];
            __builtin_amdgcn_s_setprio(1);
            #pragma unroll
            for (int ts = 0; ts < 4; ++ts) {
                bf16x8 kf0 = *(const bf16x8*)&Ks[buf][ts * 16 + lr][(lg ^ rsw) * 8];
                bf16x8 kf1 = *(const bf16x8*)&Ks[buf][ts * 16 + lr][((4 + lg) ^ rsw) * 8];
                f32x4 acc = {0.f, 0.f, 0.f, 0.f};
                acc = mfma16x16x32(kf0, qf0, acc);
                acc = mfma16x16x32(kf1, qf1, acc);
                z[ts] = acc;
            }
            __builtin_amdgcn_s_setprio(0);

            if (t == dtile) {
                #pragma unroll
                for (int ts = 0; ts < 4; ++ts)
                    #pragma unroll
                    for (int r = 0; r < 4; ++r)
                        if (t * 64 + ts * 16 + lg * 4 + r > myq) z[ts][r] = -INFINITY;
            }

            float a0 = fmaxf(fmaxf(z[0][0], z[0][1]), z[0][2]);
            float a1 = fmaxf(fmaxf(z[0][3], z[1][0]), z[1][1]);
            float a2 = fmaxf(fmaxf(z[1][2], z[1][3]), z[2][0]);
            float a3 = fmaxf(fmaxf(z[2][1], z[2][2]), z[2][3]);
            float a4 = fmaxf(fmaxf(z[3][0], z[3][1]), z[3][2]);
            float a5 = z[3][3];
            float b0 = fmaxf(fmaxf(a0, a1), a2);
            float b1 = fmaxf(fmaxf(a3, a4), a5);
            const float mt = fmaxf(b0, b1);

            if (!__all(mt <= m_run + 11.54f)) {
                float mr = fmaxf(mt, __shfl_xor(mt, 16));
                mr = fmaxf(mr, __shfl_xor(mr, 32));
                const float mnew = fmaxf(m_run, mr);
                const float alpha = fexp2(m_run - mnew);
                #pragma unroll
                for (int r = 0; r < 4; ++r) {
                    const float ar = __shfl(alpha, lg * 4 + r);
                    #pragma unroll
                    for (int hf = 0; hf < 4; ++hf) oacc[hf][r] *= ar;
                }
                l_run *= alpha;
                m_run = mnew;
            }

            float rsum = 0.f;
            #pragma unroll
            for (int ts = 0; ts < 4; ++ts) {
                bf16x4 pk;
                #pragma unroll
                for (int r = 0; r < 4; ++r) {
                    float pv = fexp2(z[ts][r] - m_run);
                    rsum += pv;
                    pk[r] = (__bf16)pv;
                }
                *(bf16x4*)&Ps[wid][lr][((ts * 2 + (lg >> 1)) ^ rsw) * 8 + (lg & 1) * 4] = pk;
            }
            l_run += rsum;

            bf16x8 pf0 = *(const bf16x8*)&Ps[wid][lr][(lg ^ rsw) * 8];
            bf16x8 pf1 = *(const bf16x8*)&Ps[wid][lr][((4 + lg) ^ rsw) * 8];
            __builtin_amdgcn_s_setprio(1);
            #pragma unroll
            for (int hf = 0; hf < 4; ++hf) {
                bf16x8 vf0 = *(const bf16x8*)&Vs[buf][hf * 16 + lr][(lg ^ rsw) * 8];
                bf16x8 vf1 = *(const bf16x8*)&Vs[buf][hf * 16 + lr][((4 + lg) ^ rsw) * 8];
                oacc[hf] = mfma16x16x32(pf0, vf0, oacc[hf]);
                oacc[hf] = mfma16x16x32(pf1, vf1, oacc[hf]);
            }
            __builtin_amdgcn_s_setprio(0);
        }

        if (pre) {
            *(bf16x8*)&Ks[buf ^ 1][srow][swz] = kr;
            *(bf16x8*)&Vs[buf ^ 1][srow][swz] = vr;
        }
        __syncthreads();
    }

    l_run += __shfl_xor(l_run, 16);
    l_run += __shfl_xor(l_run, 32);

    const float linv = 1.f / l_run;
    #pragma unroll
    for (int r = 0; r < 4; ++r) {
        const float li = __shfl(linv, lg * 4 + r);
        #pragma unroll
        for (int hf = 0; hf < 4; ++hf)
            o[(size_t)(b * SEQ + qr + lg * 4 + r) * DMODEL + h * HD + hf * 16 + lr] =
                (__bf16)(oacc[hf][r] * li);
    }
    if (lg == 0) {
        mbuf[((size_t)b * SEQ + myq) * NHEAD + h] = m_run;
        lbuf[((size_t)b * SEQ + myq) * NHEAD + h] = l_run;
    }
}

extern "C" void kernel_launch(void* const* d_in, const int* in_sizes, int n_in,
                              void* d_out, int out_size, void* d_ws, size_t ws_size,
                              hipStream_t stream) {
    const float* query = (const float*)d_in[0];
    const float* key_  = (const float*)d_in[1];
    const float* value = (const float*)d_in[2];
    const float* Wq = (const float*)d_in[3];
    const float* bq = (const float*)d_in[4];
    const float* Wk = (const float*)d_in[5];
    const float* bk = (const float*)d_in[6];
    const float* Wv = (const float*)d_in[7];
    const float* bv = (const float*)d_in[8];
    const float* Wo = (const float*)d_in[9];
    const float* bo = (const float*)d_in[10];
    float* out = (float*)d_out;

    const size_t nelem = (size_t)BC * SEQ * DMODEL;   // 8.4M
    char* p = (char*)d_ws;
    const size_t mat = nelem * sizeof(__bf16);
    __bf16* qb  = (__bf16*)p; p += mat;
    __bf16* kb  = (__bf16*)p; p += mat;
    __bf16* vtb = (__bf16*)p; p += mat;
    __bf16* ob  = (__bf16*)p; p += mat;
    const size_t wmat = (size_t)DMODEL * DMODEL * sizeof(__bf16);
    __bf16* wqb = (__bf16*)p; p += wmat;
    __bf16* wkb = (__bf16*)p; p += wmat;
    __bf16* wvb = (__bf16*)p; p += wmat;
    __bf16* wob = (__bf16*)p; p += wmat;
    float* mb = (float*)p; p += (size_t)BC * NHEAD * SEQ * sizeof(float);
    float* lb = (float*)p; p += (size_t)BC * NHEAD * SEQ * sizeof(float);

    float* wout = out + nelem;

    cvt_w<<<dim3(DMODEL * DMODEL / 2048, 4), 256, 0, stream>>>(Wq, Wk, Wv, Wo, wqb, wkb, wvb, wob);

    const int M = BC * SEQ;
    qkv_gemm<<<dim3(256, 1, 3), 512, 0, stream>>>(
        query, key_, value, wqb, wkb, wvb, bq, bk, bv, qb, kb, vtb);

    flash_fwd<<<dim3(1024), 512, 0, stream>>>(qb, kb, vtb, ob, mb, lb);

    // fused: O-projection (512 blocks) + attention-weights (1024 blocks)
    tail_fused<<<dim3(1536), 512, 0, stream>>>(ob, wob, bo, out, qb, kb, mb, lb, wout);
}

// Round 24
// 259.325 us; speedup vs baseline: 1.0146x; 1.0146x over previous
//
#include <hip/hip_runtime.h>
#include <hip/hip_bf16.h>
#include <cmath>
#include <type_traits>

#define BC     4
#define SEQ    2048
#define DMODEL 1024
#define NHEAD  16
#define HD     64
#define ASCALE 0.125f
#define LOG2E  1.44269504f

typedef __bf16 bf16x8 __attribute__((ext_vector_type(8)));
typedef __bf16 bf16x4 __attribute__((ext_vector_type(4)));
typedef float  f32x4  __attribute__((ext_vector_type(4)));

__device__ __forceinline__ f32x4 mfma16x16x32(bf16x8 a, bf16x8 b, f32x4 c) {
    return __builtin_amdgcn_mfma_f32_16x16x32_bf16(a, b, c, 0, 0, 0);
}

__device__ __forceinline__ float fexp2(float x) {   // raw v_exp_f32 (2^x)
    return __builtin_amdgcn_exp2f(x);
}

__device__ __forceinline__ void gload_lds16(const __bf16* g, __bf16* l) {
    __builtin_amdgcn_global_load_lds(
        (const __attribute__((address_space(1))) void*)g,
        (__attribute__((address_space(3))) void*)l, 16, 0, 0);
}

__global__ __launch_bounds__(256) void cvt_w(const float* __restrict__ a,
                                             const float* __restrict__ b,
                                             const float* __restrict__ c,
                                             const float* __restrict__ d,
                                             __bf16* __restrict__ oa,
                                             __bf16* __restrict__ ob,
                                             __bf16* __restrict__ oc,
                                             __bf16* __restrict__ od) {
    const float* in; __bf16* out;
    if (blockIdx.y == 0)      { in = a; out = oa; }
    else if (blockIdx.y == 1) { in = b; out = ob; }
    else if (blockIdx.y == 2) { in = c; out = oc; }
    else                      { in = d; out = od; }
    const size_t i = ((size_t)blockIdx.x * 256 + threadIdx.x) * 8;
    float4 f0 = *(const float4*)(in + i);
    float4 f1 = *(const float4*)(in + i + 4);
    bf16x8 o;
    o[0] = (__bf16)f0.x; o[1] = (__bf16)f0.y; o[2] = (__bf16)f0.z; o[3] = (__bf16)f0.w;
    o[4] = (__bf16)f1.x; o[5] = (__bf16)f1.y; o[6] = (__bf16)f1.z; o[7] = (__bf16)f1.w;
    *(bf16x8*)(out + i) = o;
}

// Batched Q/K/V projection GEMMs, 128x256 tile, 8 waves, reg-pipelined depth-1.
// XCD-locality grid decode; raw-barrier discipline (no vmcnt drain in loop).
__global__ __launch_bounds__(512) void qkv_gemm(const float* __restrict__ Aq,
                                                const float* __restrict__ Ak,
                                                const float* __restrict__ Av,
                                                const __bf16* __restrict__ Wqb,
                                                const __bf16* __restrict__ Wkb,
                                                const __bf16* __restrict__ Wvb,
                                                const float* __restrict__ bq,
                                                const float* __restrict__ bk,
                                                const float* __restrict__ bv,
                                                __bf16* __restrict__ oq,
                                                __bf16* __restrict__ ok,
                                                __bf16* __restrict__ ov) {
    constexpr int K = DMODEL, N = DMODEL;
    __shared__ __bf16 As[128 * 64];
    __shared__ __bf16 Bs[256 * 64];
    const int z = blockIdx.z;
    const float* A; const __bf16* W; const float* bias; __bf16* out; float scale; bool vt;
    if (z == 0)      { A = Aq; W = Wqb; bias = bq; out = oq; scale = ASCALE * LOG2E; vt = false; }
    else if (z == 1) { A = Ak; W = Wkb; bias = bk; out = ok; scale = 1.f; vt = false; }
    else             { A = Av; W = Wvb; bias = bv; out = ov; scale = 1.f; vt = true; }

    const int tid = threadIdx.x;
    const int lane = tid & 63;
    const int wid = tid >> 6;          // 0..7
    const int lr = lane & 15;
    const int lg = lane >> 4;
    const int wr = (wid >> 2) * 64;    // 0,64
    const int wc = (wid & 3) * 64;     // 0,64,128,192

    // XCD-locality decode (grid.x = 256): bn-siblings adjacent on one XCD
    const int flat = blockIdx.x;
    const int xcd = flat & 7;
    const int slot = flat >> 3;        // 0..31
    const int bm = (xcd + 8 * (slot >> 2)) * 128;
    const int bn = (slot & 3) * 256;

    f32x4 acc[4][4] = {};

    float4 a0[2], a1[2];   // pipelined A registers (f32, 2 chunks/thread)
    bf16x8 wreg[4];        // pipelined W registers (bf16, 4 chunks/thread)
    #pragma unroll
    for (int i = 0; i < 2; ++i) {
        const int p = tid + 512 * i;   // A chunks (128 rows x 8)
        const int row = p >> 3, c = p & 7;
        const float* ap = A + (size_t)(bm + row) * K + c * 8;
        a0[i] = ((const float4*)ap)[0];
        a1[i] = ((const float4*)ap)[1];
    }
    #pragma unroll
    for (int i = 0; i < 4; ++i) {
        const int p = tid + 512 * i;   // W chunks (256 rows x 8)
        const int row = p >> 3, c = p & 7;
        wreg[i] = *(const bf16x8*)(W + (size_t)(bn + row) * K + c * 8);
    }

    for (int k0 = 0; k0 < K; k0 += 64) {
        // commit regs loaded last iteration (per-wave vmcnt waits here)
        #pragma unroll
        for (int i = 0; i < 2; ++i) {
            const int p = tid + 512 * i;
            const int row = p >> 3, c = p & 7;
            bf16x8 v;
            v[0] = (__bf16)a0[i].x; v[1] = (__bf16)a0[i].y;
            v[2] = (__bf16)a0[i].z; v[3] = (__bf16)a0[i].w;
            v[4] = (__bf16)a1[i].x; v[5] = (__bf16)a1[i].y;
            v[6] = (__bf16)a1[i].z; v[7] = (__bf16)a1[i].w;
            *(bf16x8*)&As[row * 64 + ((c ^ (row & 7)) * 8)] = v;
        }
        #pragma unroll
        for (int i = 0; i < 4; ++i) {
            const int p = tid + 512 * i;
            const int row = p >> 3, c = p & 7;
            *(bf16x8*)&Bs[row * 64 + ((c ^ (row & 7)) * 8)] = wreg[i];
        }
        asm volatile("s_waitcnt lgkmcnt(0)" ::: "memory");   // ds_writes complete
        __builtin_amdgcn_s_barrier();                        // raw: no vmcnt drain

        if (k0 + 64 < K) {   // issue next K-step's loads; stay in flight
            #pragma unroll
            for (int i = 0; i < 2; ++i) {
                const int p = tid + 512 * i;
                const int row = p >> 3, c = p & 7;
                const float* ap = A + (size_t)(bm + row) * K + k0 + 64 + c * 8;
                a0[i] = ((const float4*)ap)[0];
                a1[i] = ((const float4*)ap)[1];
            }
            #pragma unroll
            for (int i = 0; i < 4; ++i) {
                const int p = tid + 512 * i;
                const int row = p >> 3, c = p & 7;
                wreg[i] = *(const bf16x8*)(W + (size_t)(bn + row) * K + k0 + 64 + c * 8);
            }
        }

        __builtin_amdgcn_s_setprio(1);
        #pragma unroll
        for (int kk = 0; kk < 2; ++kk) {
            bf16x8 af[4], bfg[4];
            #pragma unroll
            for (int m = 0; m < 4; ++m) {
                const int row = wr + m * 16 + lr;
                af[m] = *(const bf16x8*)&As[row * 64 + ((kk * 4 + lg) ^ (row & 7)) * 8];
            }
            #pragma unroll
            for (int n = 0; n < 4; ++n) {
                const int row = wc + n * 16 + lr;
                bfg[n] = *(const bf16x8*)&Bs[row * 64 + ((kk * 4 + lg) ^ (row & 7)) * 8];
            }
            #pragma unroll
            for (int m = 0; m < 4; ++m)
                #pragma unroll
                for (int n = 0; n < 4; ++n)
                    acc[m][n] = mfma16x16x32(af[m], bfg[n], acc[m][n]);
        }
        __builtin_amdgcn_s_setprio(0);

        __builtin_amdgcn_s_barrier();          // raw: reads done via MFMA deps
        asm volatile("" ::: "memory");
    }

    #pragma unroll
    for (int n = 0; n < 4; ++n) {
        const int col = bn + wc + n * 16 + lr;
        const float bb = bias[col];
        #pragma unroll
        for (int m = 0; m < 4; ++m) {
            const int row0 = bm + wr + m * 16 + lg * 4;
            if (vt) {
                const int h = col >> 6, hd = col & 63;
                const int b = row0 >> 11, s = row0 & 2047;
                bf16x4 pk;
                #pragma unroll
                for (int r = 0; r < 4; ++r) pk[r] = (__bf16)((acc[m][n][r] + bb) * scale);
                *(bf16x4*)(out + (((size_t)b * NHEAD + h) * HD + hd) * SEQ + s) = pk;
            } else {
                #pragma unroll
                for (int r = 0; r < 4; ++r)
                    out[(size_t)(row0 + r) * N + col] = (__bf16)((acc[m][n][r] + bb) * scale);
            }
        }
    }
}

// Fused tail: blocks [0,512) = O-projection GEMM (8-wave, 64x32 wave tile);
// blocks [512,1536) = mean-over-heads attention weights.
__global__ __launch_bounds__(512) void tail_fused(const __bf16* __restrict__ ob,
                                                  const __bf16* __restrict__ Wob,
                                                  const float* __restrict__ bo,
                                                  float* __restrict__ out,
                                                  const __bf16* __restrict__ q,
                                                  const __bf16* __restrict__ k,
                                                  const float* __restrict__ mbuf,
                                                  const float* __restrict__ lbuf,
                                                  float* __restrict__ wout) {
    __shared__ __bf16 smem[2][128][64];
    const int tid = threadIdx.x;
    const int lane = tid & 63;
    const int wid = tid >> 6;            // 0..7
    const int lr = lane & 15;
    const int lg = lane >> 4;

    if (blockIdx.x < 512) {
        // ---- O-projection: out[M,N] = ob @ Wo^T + bo (f32 out) ----
        constexpr int K = DMODEL, N = DMODEL;
        __bf16* As = &smem[0][0][0];
        __bf16* Bs = &smem[1][0][0];
        const int bx = blockIdx.x;
        const int bm = (bx & 63) * 128;
        const int bn = (bx >> 6) * 128;
        const int wr = (wid >> 2) * 64;
        const int wc = (wid & 3) * 32;

        f32x4 acc[4][2] = {};

        for (int k0 = 0; k0 < K; k0 += 64) {
            #pragma unroll
            for (int i = 0; i < 2; ++i) {
                const int p = tid + 512 * i;
                const int row = p >> 3, c = p & 7;
                const int csrc = ((c ^ (row & 7)) * 8);
                gload_lds16(Wob + (size_t)(bn + row) * K + k0 + csrc, &Bs[p * 8]);
                gload_lds16(ob  + (size_t)(bm + row) * K + k0 + csrc, &As[p * 8]);
            }
            __syncthreads();

            #pragma unroll
            for (int kk = 0; kk < 2; ++kk) {
                bf16x8 af[4], bfg[2];
                #pragma unroll
                for (int m = 0; m < 4; ++m) {
                    const int row = wr + m * 16 + lr;
                    af[m] = *(const bf16x8*)&As[row * 64 + ((kk * 4 + lg) ^ (row & 7)) * 8];
                }
                #pragma unroll
                for (int n = 0; n < 2; ++n) {
                    const int row = wc + n * 16 + lr;
                    bfg[n] = *(const bf16x8*)&Bs[row * 64 + ((kk * 4 + lg) ^ (row & 7)) * 8];
                }
                #pragma unroll
                for (int m = 0; m < 4; ++m)
                    #pragma unroll
                    for (int n = 0; n < 2; ++n)
                        acc[m][n] = mfma16x16x32(af[m], bfg[n], acc[m][n]);
            }
            __syncthreads();
        }

        #pragma unroll
        for (int n = 0; n < 2; ++n) {
            const int col = bn + wc + n * 16 + lr;
            const float bb = bo[col];
            #pragma unroll
            for (int m = 0; m < 4; ++m) {
                const int row0 = bm + wr + m * 16 + lg * 4;
                #pragma unroll
                for (int r = 0; r < 4; ++r)
                    out[(size_t)(row0 + r) * N + col] = acc[m][n][r] + bb;
            }
        }
        return;
    }

    // ---- attention weights: 128 q x 128 keys per block, 8 waves ----
    {
        const int flat = blockIdx.x - 512;   // 512 % 8 == 0 keeps XCD grouping
        const int xcd = flat & 7;
        const int slot = flat >> 3;
        const int gi = slot >> 4;
        const int st = slot & 15;
        const int b = gi & 3;
        const int t2 = (gi >> 2) ? (15 - xcd) : xcd;

        const int myq = st * 128 + wid * 16 + lr;
        const int k0 = t2 * 128;

        float* wp = wout + (size_t)(b * SEQ + myq) * SEQ + k0 + lg * 4;

        if (t2 > st) {
            const f32x4 zz = {0.f, 0.f, 0.f, 0.f};
            #pragma unroll
            for (int ts = 0; ts < 8; ++ts) *(f32x4*)(wp + ts * 16) = zz;
            return;
        }
        const bool needmask = (t2 == st);

        f32x4 rm[4], rl[4];
        {
            const float* mp = mbuf + ((size_t)b * SEQ + myq) * NHEAD;
            const float* lp = lbuf + ((size_t)b * SEQ + myq) * NHEAD;
            #pragma unroll
            for (int i = 0; i < 4; ++i) rm[i] = *(const f32x4*)(mp + i * 4);
            #pragma unroll
            for (int i = 0; i < 4; ++i) {
                f32x4 t = *(const f32x4*)(lp + i * 4);
                #pragma unroll
                for (int r = 0; r < 4; ++r) rl[i][r] = 1.f / (t[r] * (float)NHEAD);
            }
        }

        const int srow = tid >> 2;
        const int scb = (tid & 3) * 2;
        const int rsw = (lr & 7);
        const __bf16* krow = k + (size_t)(b * SEQ + k0 + srow) * DMODEL + scb * 8;
        const __bf16* qbase = q + (size_t)(b * SEQ + myq) * DMODEL + lg * 8;

        {
            bf16x8 kr[2];
            #pragma unroll
            for (int c = 0; c < 2; ++c) kr[c] = *(const bf16x8*)(krow + c * 8);
            #pragma unroll
            for (int c = 0; c < 2; ++c)
                *(bf16x8*)&smem[0][srow][((scb + c) ^ (srow & 7)) * 8] = kr[c];
        }
        bf16x8 qna = ((const bf16x8*)qbase)[0];
        bf16x8 qnb = *(const bf16x8*)(qbase + 32);

        f32x4 wacc[8] = {};
        __syncthreads();

        #pragma unroll
        for (int h = 0; h < NHEAD; ++h) {
            const int cur = h & 1;
            bf16x8 kr[2];
            if (h + 1 < NHEAD) {
                const __bf16* kp = krow + (h + 1) * HD;
                #pragma unroll
                for (int c = 0; c < 2; ++c) kr[c] = *(const bf16x8*)(kp + c * 8);
            }
            const bf16x8 qf0 = qna, qf1 = qnb;
            if (h + 1 < NHEAD) {
                qna = *(const bf16x8*)(qbase + (h + 1) * HD);
                qnb = *(const bf16x8*)(qbase + (h + 1) * HD + 32);
            }
            const float rmh = rm[h >> 2][h & 3];
            const float rlh = rl[h >> 2][h & 3];

            #pragma unroll
            for (int ts = 0; ts < 8; ++ts) {
                bf16x8 kf0 = *(const bf16x8*)&smem[cur][ts * 16 + lr][(lg ^ rsw) * 8];
                bf16x8 kf1 = *(const bf16x8*)&smem[cur][ts * 16 + lr][((4 + lg) ^ rsw) * 8];
                f32x4 zz = {0.f, 0.f, 0.f, 0.f};
                zz = mfma16x16x32(kf0, qf0, zz);
                zz = mfma16x16x32(kf1, qf1, zz);
                if (needmask) {
                    #pragma unroll
                    for (int r = 0; r < 4; ++r) {
                        float e = 0.f;
                        if (k0 + ts * 16 + lg * 4 + r <= myq)
                            e = fexp2(zz[r] - rmh) * rlh;
                        wacc[ts][r] += e;
                    }
                } else {
                    #pragma unroll
                    for (int r = 0; r < 4; ++r)
                        wacc[ts][r] += fexp2(zz[r] - rmh) * rlh;
                }
            }

            if (h + 1 < NHEAD) {
                #pragma unroll
                for (int c = 0; c < 2; ++c)
                    *(bf16x8*)&smem[cur ^ 1][srow][((scb + c) ^ (srow & 7)) * 8] = kr[c];
            }
            __syncthreads();
        }

        #pragma unroll
        for (int ts = 0; ts < 8; ++ts)
            *(f32x4*)(wp + ts * 16) = wacc[ts];
    }
}

// Causal flash attention, 128 q rows x 8 waves per block, log2-domain softmax.
// Lazy row-max + per-lane partial l.
__global__ __launch_bounds__(512) void flash_fwd(const __bf16* __restrict__ q,
                                                 const __bf16* __restrict__ k,
                                                 const __bf16* __restrict__ vt,
                                                 __bf16* __restrict__ o,
                                                 float* __restrict__ mbuf,
                                                 float* __restrict__ lbuf) {
    __shared__ __bf16 Ks[2][64][64];
    __shared__ __bf16 Vs[2][64][64];   // transposed: [hd][t]
    __shared__ __bf16 Ps[8][16][64];
    const int tid = threadIdx.x;
    const int lane = tid & 63;
    const int wid = tid >> 6;          // 0..7
    const int lr = lane & 15;
    const int lg = lane >> 4;

    const int flat = blockIdx.x;       // grid = 1024
    const int xcd = flat & 7;
    const int slot = flat >> 3;        // 0..127
    const int group = xcd * 8 + (slot >> 4);   // 0..63 = (b,h)
    const int b = group >> 4;
    const int h = group & 15;
    const int qt = 15 - (slot & 15);   // 128-row q tile index

    const int qr = qt * 128 + wid * 16;
    const int myq = qr + lr;
    const int dtile = qr >> 6;

    bf16x8 qf0, qf1;
    {
        const __bf16* qp = q + (size_t)(b * SEQ + myq) * DMODEL + h * HD + lg * 8;
        qf0 = ((const bf16x8*)qp)[0];
        qf1 = *(const bf16x8*)(qp + 32);
    }

    float m_run = -INFINITY;
    float l_run = 0.f;
    f32x4 oacc[4] = {};

    const int srow = tid >> 3;
    const int sc = tid & 7;
    const int swz = (sc ^ (srow & 7)) * 8;
    const int rsw = (lr & 7);
    const int nt = 2 * qt + 2;

    const __bf16* kbase = k + (size_t)(b * SEQ + srow) * DMODEL + h * HD + sc * 8;
    const __bf16* vbase = vt + ((size_t)(b * NHEAD + h) * HD + srow) * SEQ + sc * 8;

    {
        bf16x8 kr = *(const bf16x8*)kbase;
        bf16x8 vr = *(const bf16x8*)vbase;
        *(bf16x8*)&Ks[0][srow][swz] = kr;
        *(bf16x8*)&Vs[0][srow][swz] = vr;
    }
    __syncthreads();

    for (int t = 0; t < nt; ++t) {
        const int buf = t & 1;
        const bool pre = (t + 1 < nt);
        bf16x8 kr, vr;
        if (pre) {
            kr = *(const bf16x8*)(kbase + (size_t)(t + 1) * 64 * DMODEL);
            vr = *(const bf16x8*)(vbase + (t + 1) * 64);
        }

        if (t <= dtile) {
            f32x4 z[4];
            __builtin_amdgcn_s_setprio(1);
            #pragma unroll
            for (int ts = 0; ts < 4; ++ts) {
                bf16x8 kf0 = *(const bf16x8*)&Ks[buf][ts * 16 + lr][(lg ^ rsw) * 8];
                bf16x8 kf1 = *(const bf16x8*)&Ks[buf][ts * 16 + lr][((4 + lg) ^ rsw) * 8];
                f32x4 acc = {0.f, 0.f, 0.f, 0.f};
                acc = mfma16x16x32(kf0, qf0, acc);
                acc = mfma16x16x32(kf1, qf1, acc);
                z[ts] = acc;
            }
            __builtin_amdgcn_s_setprio(0);

            if (t == dtile) {
                #pragma unroll
                for (int ts = 0; ts < 4; ++ts)
                    #pragma unroll
                    for (int r = 0; r < 4; ++r)
                        if (t * 64 + ts * 16 + lg * 4 + r > myq) z[ts][r] = -INFINITY;
            }

            float a0 = fmaxf(fmaxf(z[0][0], z[0][1]), z[0][2]);
            float a1 = fmaxf(fmaxf(z[0][3], z[1][0]), z[1][1]);
            float a2 = fmaxf(fmaxf(z[1][2], z[1][3]), z[2][0]);
            float a3 = fmaxf(fmaxf(z[2][1], z[2][2]), z[2][3]);
            float a4 = fmaxf(fmaxf(z[3][0], z[3][1]), z[3][2]);
            float a5 = z[3][3];
            float b0 = fmaxf(fmaxf(a0, a1), a2);
            float b1 = fmaxf(fmaxf(a3, a4), a5);
            const float mt = fmaxf(b0, b1);

            if (!__all(mt <= m_run + 11.54f)) {
                float mr = fmaxf(mt, __shfl_xor(mt, 16));
                mr = fmaxf(mr, __shfl_xor(mr, 32));
                const float mnew = fmaxf(m_run, mr);
                const float alpha = fexp2(m_run - mnew);
                #pragma unroll
                for (int r = 0; r < 4; ++r) {
                    const float ar = __shfl(alpha, lg * 4 + r);
                    #pragma unroll
                    for (int hf = 0; hf < 4; ++hf) oacc[hf][r] *= ar;
                }
                l_run *= alpha;
                m_run = mnew;
            }

            float rsum = 0.f;
            #pragma unroll
            for (int ts = 0; ts < 4; ++ts) {
                bf16x4 pk;
                #pragma unroll
                for (int r = 0; r < 4; ++r) {
                    float pv = fexp2(z[ts][r] - m_run);
                    rsum += pv;
                    pk[r] = (__bf16)pv;
                }
                *(bf16x4*)&Ps[wid][lr][((ts * 2 + (lg >> 1)) ^ rsw) * 8 + (lg & 1) * 4] = pk;
            }
            l_run += rsum;

            bf16x8 pf0 = *(const bf16x8*)&Ps[wid][lr][(lg ^ rsw) * 8];
            bf16x8 pf1 = *(const bf16x8*)&Ps[wid][lr][((4 + lg) ^ rsw) * 8];
            __builtin_amdgcn_s_setprio(1);
            #pragma unroll
            for (int hf = 0; hf < 4; ++hf) {
                bf16x8 vf0 = *(const bf16x8*)&Vs[buf][hf * 16 + lr][(lg ^ rsw) * 8];
                bf16x8 vf1 = *(const bf16x8*)&Vs[buf][hf * 16 + lr][((4 + lg) ^ rsw) * 8];
                oacc[hf] = mfma16x16x32(pf0, vf0, oacc[hf]);
                oacc[hf] = mfma16x16x32(pf1, vf1, oacc[hf]);
            }
            __builtin_amdgcn_s_setprio(0);
        }

        if (pre) {
            *(bf16x8*)&Ks[buf ^ 1][srow][swz] = kr;
            *(bf16x8*)&Vs[buf ^ 1][srow][swz] = vr;
        }
        __syncthreads();
    }

    l_run += __shfl_xor(l_run, 16);
    l_run += __shfl_xor(l_run, 32);

    const float linv = 1.f / l_run;
    #pragma unroll
    for (int r = 0; r < 4; ++r) {
        const float li = __shfl(linv, lg * 4 + r);
        #pragma unroll
        for (int hf = 0; hf < 4; ++hf)
            o[(size_t)(b * SEQ + qr + lg * 4 + r) * DMODEL + h * HD + hf * 16 + lr] =
                (__bf16)(oacc[hf][r] * li);
    }
    if (lg == 0) {
        mbuf[((size_t)b * SEQ + myq) * NHEAD + h] = m_run;
        lbuf[((size_t)b * SEQ + myq) * NHEAD + h] = l_run;
    }
}

extern "C" void kernel_launch(void* const* d_in, const int* in_sizes, int n_in,
                              void* d_out, int out_size, void* d_ws, size_t ws_size,
                              hipStream_t stream) {
    const float* query = (const float*)d_in[0];
    const float* key_  = (const float*)d_in[1];
    const float* value = (const float*)d_in[2];
    const float* Wq = (const float*)d_in[3];
    const float* bq = (const float*)d_in[4];
    const float* Wk = (const float*)d_in[5];
    const float* bk = (const float*)d_in[6];
    const float* Wv = (const float*)d_in[7];
    const float* bv = (const float*)d_in[8];
    const float* Wo = (const float*)d_in[9];
    const float* bo = (const float*)d_in[10];
    float* out = (float*)d_out;

    const size_t nelem = (size_t)BC * SEQ * DMODEL;   // 8.4M
    char* p = (char*)d_ws;
    const size_t mat = nelem * sizeof(__bf16);
    __bf16* qb  = (__bf16*)p; p += mat;
    __bf16* kb  = (__bf16*)p; p += mat;
    __bf16* vtb = (__bf16*)p; p += mat;
    __bf16* ob  = (__bf16*)p; p += mat;
    const size_t wmat = (size_t)DMODEL * DMODEL * sizeof(__bf16);
    __bf16* wqb = (__bf16*)p; p += wmat;
    __bf16* wkb = (__bf16*)p; p += wmat;
    __bf16* wvb = (__bf16*)p; p += wmat;
    __bf16* wob = (__bf16*)p; p += wmat;
    float* mb = (float*)p; p += (size_t)BC * NHEAD * SEQ * sizeof(float);
    float* lb = (float*)p; p += (size_t)BC * NHEAD * SEQ * sizeof(float);

    float* wout = out + nelem;

    cvt_w<<<dim3(DMODEL * DMODEL / 2048, 4), 256, 0, stream>>>(Wq, Wk, Wv, Wo, wqb, wkb, wvb, wob);

    const int M = BC * SEQ;
    qkv_gemm<<<dim3(256, 1, 3), 512, 0, stream>>>(
        query, key_, value, wqb, wkb, wvb, bq, bk, bv, qb, kb, vtb);

    flash_fwd<<<dim3(1024), 512, 0, stream>>>(qb, kb, vtb, ob, mb, lb);

    // fused: O-projection (512 blocks) + attention-weights (1024 blocks)
    tail_fused<<<dim3(1536), 512, 0, stream>>>(ob, wob, bo, out, qb, kb, mb, lb, wout);
}